// Round 16
// baseline (183.081 us; speedup 1.0000x reference)
//
#include <hip/hip_runtime.h>

#define HH 299
#define WW 299
#define HW (HH * WW)
#define BORDER 3
#define NT 256
#define RPB 4
#define CHUNKS 75            // ceil(299/4)
#define INV299 (1.0f / 299.0f)

typedef float f4 __attribute__((ext_vector_type(4)));
typedef f4 __attribute__((aligned(4))) f4a;   // 4B-aligned float4 loads

__global__ __launch_bounds__(NT) void crop_resize_kernel(
    const float* __restrict__ x,   // (S, 3, H, W)
    const int*   __restrict__ f,   // (S, G, 4)
    float*       __restrict__ out, // (S, G, 3, H, W)
    int G)
{
    __shared__ float sV[RPB][3][304];   // fused vertical rows, 14.6 KB

    // Bijective XCD swizzle (grid = 38400 = 8 * 4800): contiguous logical
    // chunks per XCD -> a crop's blocks (and its image) stay in one L2.
    int cpx = (int)(gridDim.x >> 3);
    int hb  = blockIdx.x;
    int blk = (hb & 7) * cpx + (hb >> 3);

    int sg = blk / CHUNKS;               // crop index si*G + gi
    int r0 = (blk - sg * CHUNKS) * RPB;  // first output row of this block
    int si = sg / G;

    const int* box = f + (sg << 2);
    int tlx = max(box[0] - BORDER, 0);
    int tly = max(box[1] - BORDER, 0);
    int hc  = min(box[2] + BORDER, HH - 1) - tlx;
    int wc  = min(box[3] + BORDER, WW - 1) - tly;

    int t = threadIdx.x;
    const float* img = x + si * 3 * HW;

    // Row (x-axis) coords for RPB rows — block-uniform, division-free.
    float hstep = (float)hc * INV299;
    int   gxb[RPB]; float fxa[RPB];
    #pragma unroll
    for (int r = 0; r < RPB; ++r) {
        int row = min(r0 + r, HH - 1);           // tail dup is harmless
        float sx = fmaf((float)row + 0.5f, hstep, -0.5f);
        sx = fminf(fmaxf(sx, 0.0f), (float)hc - 1.0f);
        int bx = max(min((int)floorf(sx), hc - 2), 0);
        fxa[r] = sx - (float)bx;
        gxb[r] = tlx + bx;
    }

    // Staging: unit u in [0, RPB*228): r = u/228, ch = (u%228)/76, quad q.
    // 912 units over 256 threads -> 4 passes, all loads independent.
    #pragma unroll
    for (int pass = 0; pass < 4; ++pass) {
        int u = t + pass * NT;
        if (u < RPB * 228) {
            int r  = u / 228;
            int m  = u - r * 228;
            int ch = m / 76;
            int q  = (m - ch * 76) << 2;
            if (q < wc) {
                int c = min(q, wc - 3);          // 16B read stays inside row
                const float* p = img + ch * HW + gxb[r] * WW + tly + c;
                f4 a = *(const f4a*)p;           // source row bx
                f4 b = *(const f4a*)(p + WW);    // source row bx+1
                float fr = fxa[r], om = 1.0f - fr;
                sV[r][ch][c + 0] = fmaf(a.x, om, b.x * fr);
                sV[r][ch][c + 1] = fmaf(a.y, om, b.y * fr);
                sV[r][ch][c + 2] = fmaf(a.z, om, b.z * fr);
                sV[r][ch][c + 3] = fmaf(a.w, om, b.w * fr);
            }
        }
    }
    __syncthreads();

    // Output: col j per thread (2 passes: 256 + ragged 43). NT stores:
    // output lines are never re-read -> don't let them thrash L2.
    for (int j = t; j < WW; j += NT) {
        float sy = fmaf((float)j + 0.5f, (float)wc * INV299, -0.5f);
        sy = fminf(fmaxf(sy, 0.0f), (float)wc - 1.0f);
        int by = max(min((int)floorf(sy), wc - 2), 0);
        float fy   = sy - (float)by;
        float omfy = 1.0f - fy;

        #pragma unroll
        for (int r = 0; r < RPB; ++r) {
            int row = r0 + r;
            if (row < HH) {                      // uniform guard (tail block)
                int obase = (sg * 3 * HH + row) * WW + j;
                #pragma unroll
                for (int ch = 0; ch < 3; ++ch) {
                    float v = fmaf(sV[r][ch][by], omfy, sV[r][ch][by + 1] * fy);
                    __builtin_nontemporal_store(v, out + obase + ch * HW);
                }
            }
        }
    }
}

extern "C" void kernel_launch(void* const* d_in, const int* in_sizes, int n_in,
                              void* d_out, int out_size, void* d_ws, size_t ws_size,
                              hipStream_t stream) {
    const float* x = (const float*)d_in[0];
    const int*   f = (const int*)d_in[1];
    float* out = (float*)d_out;

    int S = in_sizes[0] / (3 * HW);   // 32
    int G = in_sizes[1] / (S * 4);    // 16

    dim3 grid((unsigned)(S * G * CHUNKS));  // 38400 = 8 * 4800
    dim3 block(NT);
    crop_resize_kernel<<<grid, block, 0, stream>>>(x, f, out, G);
}

// Round 17
// 170.306 us; speedup vs baseline: 1.0750x; 1.0750x over previous
//
#include <hip/hip_runtime.h>

#define HH 299
#define WW 299
#define HW (HH * WW)
#define BORDER 3
#define NT 256
#define RPB 4
#define CHUNKS 75            // ceil(299/4)
#define INV299 (1.0f / 299.0f)

typedef float f4 __attribute__((ext_vector_type(4)));
typedef f4 __attribute__((aligned(4))) f4a;   // 4B-aligned float4 loads

__global__ __launch_bounds__(NT) void crop_resize_kernel(
    const float* __restrict__ x,   // (S, 3, H, W)
    const int*   __restrict__ f,   // (S, G, 4)
    float*       __restrict__ out, // (S, G, 3, H, W)
    int G)
{
    __shared__ float sV[RPB][3][304];   // fused vertical rows, 14.6 KB

    // A/B probe: NO XCD swizzle — default round-robin block placement.
    int blk = blockIdx.x;

    int sg = blk / CHUNKS;               // crop index si*G + gi
    int r0 = (blk - sg * CHUNKS) * RPB;  // first output row of this block
    int si = sg / G;

    const int* box = f + (sg << 2);
    int tlx = max(box[0] - BORDER, 0);
    int tly = max(box[1] - BORDER, 0);
    int hc  = min(box[2] + BORDER, HH - 1) - tlx;
    int wc  = min(box[3] + BORDER, WW - 1) - tly;

    int t = threadIdx.x;
    const float* img = x + si * 3 * HW;

    // Row (x-axis) coords for RPB rows — block-uniform, division-free.
    float hstep = (float)hc * INV299;
    int   gxb[RPB]; float fxa[RPB];
    #pragma unroll
    for (int r = 0; r < RPB; ++r) {
        int row = min(r0 + r, HH - 1);           // tail dup is harmless
        float sx = fmaf((float)row + 0.5f, hstep, -0.5f);
        sx = fminf(fmaxf(sx, 0.0f), (float)hc - 1.0f);
        int bx = max(min((int)floorf(sx), hc - 2), 0);
        fxa[r] = sx - (float)bx;
        gxb[r] = tlx + bx;
    }

    // Staging: unit u in [0, RPB*228): r = u/228, ch = (u%228)/76, quad q.
    // 912 units over 256 threads -> 4 passes, all loads independent.
    #pragma unroll
    for (int pass = 0; pass < 4; ++pass) {
        int u = t + pass * NT;
        if (u < RPB * 228) {
            int r  = u / 228;
            int m  = u - r * 228;
            int ch = m / 76;
            int q  = (m - ch * 76) << 2;
            if (q < wc) {
                int c = min(q, wc - 3);          // 16B read stays inside row
                const float* p = img + ch * HW + gxb[r] * WW + tly + c;
                f4 a = *(const f4a*)p;           // source row bx
                f4 b = *(const f4a*)(p + WW);    // source row bx+1
                float fr = fxa[r], om = 1.0f - fr;
                sV[r][ch][c + 0] = fmaf(a.x, om, b.x * fr);
                sV[r][ch][c + 1] = fmaf(a.y, om, b.y * fr);
                sV[r][ch][c + 2] = fmaf(a.z, om, b.z * fr);
                sV[r][ch][c + 3] = fmaf(a.w, om, b.w * fr);
            }
        }
    }
    __syncthreads();

    // Output: col j per thread (2 passes: 256 + ragged 43).
    for (int j = t; j < WW; j += NT) {
        float sy = fmaf((float)j + 0.5f, (float)wc * INV299, -0.5f);
        sy = fminf(fmaxf(sy, 0.0f), (float)wc - 1.0f);
        int by = max(min((int)floorf(sy), wc - 2), 0);
        float fy   = sy - (float)by;
        float omfy = 1.0f - fy;

        #pragma unroll
        for (int r = 0; r < RPB; ++r) {
            int row = r0 + r;
            if (row < HH) {                      // uniform guard (tail block)
                int obase = (sg * 3 * HH + row) * WW + j;
                #pragma unroll
                for (int ch = 0; ch < 3; ++ch) {
                    out[obase + ch * HW] =
                        fmaf(sV[r][ch][by], omfy, sV[r][ch][by + 1] * fy);
                }
            }
        }
    }
}

extern "C" void kernel_launch(void* const* d_in, const int* in_sizes, int n_in,
                              void* d_out, int out_size, void* d_ws, size_t ws_size,
                              hipStream_t stream) {
    const float* x = (const float*)d_in[0];
    const int*   f = (const int*)d_in[1];
    float* out = (float*)d_out;

    int S = in_sizes[0] / (3 * HW);   // 32
    int G = in_sizes[1] / (S * 4);    // 16

    dim3 grid((unsigned)(S * G * CHUNKS));  // 38400
    dim3 block(NT);
    crop_resize_kernel<<<grid, block, 0, stream>>>(x, f, out, G);
}

// Round 18
// 151.578 us; speedup vs baseline: 1.2078x; 1.1236x over previous
//
#include <hip/hip_runtime.h>

#define HH 299
#define WW 299
#define HW (HH * WW)
#define BORDER 3
#define NT 256
#define RPB 4
#define CHUNKS 75            // ceil(299/4)
#define INV299 (1.0f / 299.0f)

typedef float f4 __attribute__((ext_vector_type(4)));
typedef f4 __attribute__((aligned(4))) f4a;   // 4B-aligned float4 loads

__global__ __launch_bounds__(NT) void crop_resize_kernel(
    const float* __restrict__ x,   // (S, 3, H, W)
    const int*   __restrict__ f,   // (S, G, 4)
    float*       __restrict__ out, // (S, G, 3, H, W)
    int G)
{
    __shared__ float sV[RPB][3][304];   // fused vertical rows, 14.6 KB

    // Bijective XCD swizzle (grid = 38400 = 8 * 4800): contiguous logical
    // chunks per XCD -> a crop's blocks (and its image) stay in one L2.
    // Isolated A/B (R14 vs R17): swizzle = +11%. Keep.
    int cpx = (int)(gridDim.x >> 3);
    int hb  = blockIdx.x;
    int blk = (hb & 7) * cpx + (hb >> 3);

    int sg = blk / CHUNKS;               // crop index si*G + gi
    int r0 = (blk - sg * CHUNKS) * RPB;  // first output row of this block
    int si = sg / G;

    const int* box = f + (sg << 2);
    int tlx = max(box[0] - BORDER, 0);
    int tly = max(box[1] - BORDER, 0);
    int hc  = min(box[2] + BORDER, HH - 1) - tlx;
    int wc  = min(box[3] + BORDER, WW - 1) - tly;

    int t = threadIdx.x;
    const float* img = x + si * 3 * HW;

    // Row (x-axis) coords for RPB rows — block-uniform, division-free.
    float hstep = (float)hc * INV299;
    int   gxb[RPB]; float fxa[RPB];
    #pragma unroll
    for (int r = 0; r < RPB; ++r) {
        int row = min(r0 + r, HH - 1);           // tail dup is harmless
        float sx = fmaf((float)row + 0.5f, hstep, -0.5f);
        sx = fminf(fmaxf(sx, 0.0f), (float)hc - 1.0f);
        int bx = max(min((int)floorf(sx), hc - 2), 0);
        fxa[r] = sx - (float)bx;
        gxb[r] = tlx + bx;
    }

    // Staging: unit u in [0, RPB*228): r = u/228, ch = (u%228)/76, quad q.
    // 912 units over 256 threads -> 4 passes, all loads independent.
    #pragma unroll
    for (int pass = 0; pass < 4; ++pass) {
        int u = t + pass * NT;
        if (u < RPB * 228) {
            int r  = u / 228;
            int m  = u - r * 228;
            int ch = m / 76;
            int q  = (m - ch * 76) << 2;
            if (q < wc) {
                int c = min(q, wc - 3);          // 16B read stays inside row
                const float* p = img + ch * HW + gxb[r] * WW + tly + c;
                f4 a = *(const f4a*)p;           // source row bx
                f4 b = *(const f4a*)(p + WW);    // source row bx+1
                float fr = fxa[r], om = 1.0f - fr;
                sV[r][ch][c + 0] = fmaf(a.x, om, b.x * fr);
                sV[r][ch][c + 1] = fmaf(a.y, om, b.y * fr);
                sV[r][ch][c + 2] = fmaf(a.z, om, b.z * fr);
                sV[r][ch][c + 3] = fmaf(a.w, om, b.w * fr);
            }
        }
    }
    __syncthreads();

    // Output: col j per thread (2 passes: 256 + ragged 43).
    for (int j = t; j < WW; j += NT) {
        float sy = fmaf((float)j + 0.5f, (float)wc * INV299, -0.5f);
        sy = fminf(fmaxf(sy, 0.0f), (float)wc - 1.0f);
        int by = max(min((int)floorf(sy), wc - 2), 0);
        float fy   = sy - (float)by;
        float omfy = 1.0f - fy;

        #pragma unroll
        for (int r = 0; r < RPB; ++r) {
            int row = r0 + r;
            if (row < HH) {                      // uniform guard (tail block)
                int obase = (sg * 3 * HH + row) * WW + j;
                #pragma unroll
                for (int ch = 0; ch < 3; ++ch) {
                    out[obase + ch * HW] =
                        fmaf(sV[r][ch][by], omfy, sV[r][ch][by + 1] * fy);
                }
            }
        }
    }
}

extern "C" void kernel_launch(void* const* d_in, const int* in_sizes, int n_in,
                              void* d_out, int out_size, void* d_ws, size_t ws_size,
                              hipStream_t stream) {
    const float* x = (const float*)d_in[0];
    const int*   f = (const int*)d_in[1];
    float* out = (float*)d_out;

    int S = in_sizes[0] / (3 * HW);   // 32
    int G = in_sizes[1] / (S * 4);    // 16

    dim3 grid((unsigned)(S * G * CHUNKS));  // 38400 = 8 * 4800
    dim3 block(NT);
    crop_resize_kernel<<<grid, block, 0, stream>>>(x, f, out, G);
}